// Round 7
// baseline (11772.800 us; speedup 1.0000x reference)
//
#include <hip/hip_runtime.h>
#include <stdint.h>

#define T_LEN 4096
#define HID   400
#define G4    1600
#define KDIM  300
#define STACKN 32

__device__ __forceinline__ float fsig(float x){ return 1.f/(1.f + __expf(-x)); }
__device__ __forceinline__ float ftanh(float x){ float e = __expf(2.f*x); return 1.f - 2.f/(e+1.f); }

__device__ __forceinline__ float wait_tag(const unsigned long long* p, unsigned want){
  unsigned long long ex;
  do { ex = __hip_atomic_load(p, __ATOMIC_RELAXED, __HIP_MEMORY_SCOPE_AGENT); }
  while ((unsigned)(ex >> 32) != want);
  union{unsigned u; float f;} c; c.u = (unsigned)ex; return c.f;
}
__device__ __forceinline__ void pub_tag(unsigned long long* p, unsigned tag, float v){
  union{unsigned u; float f;} c; c.f = v;
  __hip_atomic_store(p, ((unsigned long long)tag << 32) | (unsigned long long)c.u,
                     __ATOMIC_RELAXED, __HIP_MEMORY_SCOPE_AGENT);
}
__device__ __forceinline__ void wait_ge(const unsigned* p, unsigned want){
  while (__hip_atomic_load(p, __ATOMIC_RELAXED, __HIP_MEMORY_SCOPE_AGENT) < want) {}
}
__device__ __forceinline__ void set_prog(unsigned* p, unsigned v){
  __hip_atomic_store(p, v, __ATOMIC_RELAXED, __HIP_MEMORY_SCOPE_AGENT);
}

// ---------------- init credit counters (poison would defeat backpressure) ----------------
__global__ void kinit(unsigned* p){ p[threadIdx.x] = 0u; }

// ---------------- layer-0 xg GEMM with fused embedding gather (K=150, f32) ----------------
__global__ void __launch_bounds__(256) kgemm0(
    const int* __restrict__ xma, const int* __restrict__ xcpc, const int* __restrict__ xr,
    const float* __restrict__ em, const float* __restrict__ ec, const float* __restrict__ er,
    const float* __restrict__ W, const float* __restrict__ b1, const float* __restrict__ b2,
    float* __restrict__ XG)
{
  __shared__ float xs[8*152];
  const int t0 = blockIdx.x*8;
  const int tid = threadIdx.x;
  for (int idx = tid; idx < 8*150; idx += 256){
    int tt = idx / 150, k = idx - tt*150;
    int t = t0 + tt;
    float v;
    if (k < 50)       v = em[(size_t)xma[t]*50 + k];
    else if (k < 100) v = ec[(size_t)xcpc[t]*50 + (k-50)];
    else              v = er[(size_t)xr[t]*50 + (k-100)];
    xs[tt*152 + k] = v;
  }
  __syncthreads();
  int r = blockIdx.y*256 + tid;
  if (r >= G4) return;
  float acc[8];
  #pragma unroll
  for (int i=0;i<8;i++) acc[i]=0.f;
  const float2* wr = (const float2*)(W + (size_t)r*150);
  for (int k2=0;k2<75;k2++){
    float2 w = wr[k2];
    int k = 2*k2;
    #pragma unroll
    for (int tt=0;tt<8;tt++)
      acc[tt] += w.x*xs[tt*152+k] + w.y*xs[tt*152+k+1];
  }
  float bb = b1[r] + b2[r];
  #pragma unroll
  for (int tt=0;tt<8;tt++)
    XG[(size_t)(t0+tt)*G4 + r] = acc[tt] + bb;
}

// ================== fused 2-layer pipelined LSTM scan (no FF stage) ==================
// 32 WGs: [0,16) L0 recurrence; [16,32) L1 recurrence with Wih1 folded in
// (each L1 lane holds both Whh1 and Wih1 row-slices; xg1 computed in-place).
// Round-4-proven 3-barrier skeleton + wave-uniform broadcast matvec (part = wave&3,
// all 64 lanes read the same LDS address -> broadcast, conflict-free).
// Credit backpressure (hbufA: L0 may not overwrite tag t-7 until all L1 WGs consumed it)
// runs on a DEDICATED idle wave, concurrent with the staging polls (round-6's mistake:
// credits appended serially to a staging wave's exec-masked path).
// Handshake: u64 {tag hi32, f32 lo32}, relaxed agent atomics, depth-8 slots.
// Tags 1..T never collide with 0x00/0xAA fill patterns.
__global__ void __launch_bounds__(512,1) kpipe(
    const float* __restrict__ XG0,
    const float* __restrict__ Whh0, const float* __restrict__ Whh1,
    const float* __restrict__ Wih1, const float* __restrict__ bih1,
    const float* __restrict__ bhh1,
    float* __restrict__ RN,
    unsigned long long* hbufA, unsigned long long* hbufB,
    unsigned* l1p, int T)
{
  const int wid  = blockIdx.x;
  const int tid  = threadIdx.x;
  const int wave = tid >> 6;          // 0..7
  const int lane = tid & 63;
  const int part = wave & 3;          // k-slice [part*100, part*100+100)
  const int mrow = (wave>>2)*50 + lane;   // matvec row 0..99 (valid lane<50)
  const bool domat = (lane < 50);

  __shared__ float lds_h[400];        // h (L0) / h1 (L1)
  __shared__ float lds_h0[400];       // L1 only: h0(t+1) from layer 0
  __shared__ float lds_part[400];
  __shared__ float lds_hnew[25];

  if (wid < 16){
    // ---------------- layer-0 recurrence ----------------
    const int w = wid;
    float4 w4[25];
    if (domat){
      int gate = mrow/25, jj = mrow%25;
      const float4* wr = (const float4*)(Whh0 + (size_t)(gate*400 + w*25 + jj)*HID) + part*25;
      #pragma unroll
      for (int i=0;i<25;i++) w4[i] = wr[i];
    }
    const int j = w*25 + tid;          // valid for tid<25
    float c = 0.f;
    for (int t=0; t<T; t++){
      float xgi=0,xgf=0,xgg=0,xgo=0;
      if (tid < 25){
        const float* xrw = XG0 + (size_t)t*G4;
        xgi=xrw[j]; xgf=xrw[400+j]; xgg=xrw[800+j]; xgo=xrw[1200+j];
      }
      if (tid < 400){                  // staging: waves 0..6
        float hv = 0.f;
        if (t > 0){
          if (tid >= w*25 && tid < w*25+25) hv = lds_hnew[tid - w*25];
          else hv = wait_tag(hbufA + (size_t)(t&7)*HID + tid, (unsigned)t);
        }
        lds_h[tid] = hv;
      } else if (tid >= 448 && tid < 464){
        // credit on wave 7 (concurrent with staging): L1 WG i consumed hbufA tag t-7
        wait_ge(&l1p[tid-448], (unsigned)(t>=7 ? t-7 : 0));
      }
      __syncthreads();
      if (domat){
        const float4* hp = (const float4*)(lds_h + part*100);
        float sum = 0.f;
        #pragma unroll
        for (int i=0;i<25;i++){
          float4 h4 = hp[i];
          sum += w4[i].x*h4.x + w4[i].y*h4.y + w4[i].z*h4.z + w4[i].w*h4.w;
        }
        lds_part[part*100 + mrow] = sum;
      }
      __syncthreads();
      if (tid < 25){
        float s0 = lds_part[tid]    + lds_part[100+tid] + lds_part[200+tid] + lds_part[300+tid];
        float s1 = lds_part[25+tid] + lds_part[125+tid] + lds_part[225+tid] + lds_part[325+tid];
        float s2 = lds_part[50+tid] + lds_part[150+tid] + lds_part[250+tid] + lds_part[350+tid];
        float s3 = lds_part[75+tid] + lds_part[175+tid] + lds_part[275+tid] + lds_part[375+tid];
        float gi = xgi+s0, gf = xgf+s1, gg = xgg+s2, go = xgo+s3;
        c = fsig(gf)*c + fsig(gi)*ftanh(gg);
        float h = fsig(go)*ftanh(c);
        pub_tag(hbufA + (size_t)((t+1)&7)*HID + j, (unsigned)(t+1), h);
        lds_hnew[tid] = h;
      }
      __syncthreads();
    }
  } else {
    // ---------------- layer-1 recurrence, Wih1 folded in ----------------
    const int l = wid - 16;
    float4 w4[25];   // Whh1 row-slice
    float4 u4[25];   // Wih1 row-slice
    if (domat){
      int gate = mrow/25, jj = mrow%25;
      int row = gate*400 + l*25 + jj;
      const float4* wr = (const float4*)(Whh1 + (size_t)row*HID) + part*25;
      const float4* ur = (const float4*)(Wih1 + (size_t)row*HID) + part*25;
      #pragma unroll
      for (int i=0;i<25;i++){ w4[i] = wr[i]; u4[i] = ur[i]; }
    }
    const int j = l*25 + tid;          // valid for tid<25
    float bi=0,bf=0,bg=0,bo=0;
    if (tid < 25){
      bi = bih1[j]        + bhh1[j];
      bf = bih1[400+j]    + bhh1[400+j];
      bg = bih1[800+j]    + bhh1[800+j];
      bo = bih1[1200+j]   + bhh1[1200+j];
    }
    float c = 0.f;
    for (int t=0; t<T; t++){
      if (tid < 400){
        // dual interleaved poll: h1(t) from hbufB peers, h0(t+1) from hbufA
        const unsigned long long* pB = hbufB + (size_t)(t&7)*HID + tid;
        const unsigned long long* pA = hbufA + (size_t)((t+1)&7)*HID + tid;
        const bool own = (tid >= l*25 && tid < l*25+25);
        bool d1 = (t==0) || own;
        bool d0 = false;
        float h1v = 0.f, h0v = 0.f;
        while (!(d0 && d1)){
          if (!d1){
            unsigned long long e = __hip_atomic_load(pB, __ATOMIC_RELAXED, __HIP_MEMORY_SCOPE_AGENT);
            if ((unsigned)(e >> 32) == (unsigned)t){
              union{unsigned u; float f;} cv; cv.u = (unsigned)e; h1v = cv.f; d1 = true;
            }
          }
          if (!d0){
            unsigned long long e = __hip_atomic_load(pA, __ATOMIC_RELAXED, __HIP_MEMORY_SCOPE_AGENT);
            if ((unsigned)(e >> 32) == (unsigned)(t+1)){
              union{unsigned u; float f;} cv; cv.u = (unsigned)e; h0v = cv.f; d0 = true;
            }
          }
        }
        if (own && t > 0) h1v = lds_hnew[tid - l*25];
        lds_h[tid]  = h1v;
        lds_h0[tid] = h0v;
      }
      __syncthreads();
      if (tid == 447) set_prog(&l1p[l], (unsigned)(t+1));   // hbufA slot (t+1)&7 consumed
      if (domat){
        const float4* hp1 = (const float4*)(lds_h  + part*100);
        const float4* hp0 = (const float4*)(lds_h0 + part*100);
        float sum = 0.f;
        #pragma unroll
        for (int i=0;i<25;i++){
          float4 h4 = hp1[i];
          float4 x4 = hp0[i];
          sum += w4[i].x*h4.x + w4[i].y*h4.y + w4[i].z*h4.z + w4[i].w*h4.w;
          sum += u4[i].x*x4.x + u4[i].y*x4.y + u4[i].z*x4.z + u4[i].w*x4.w;
        }
        lds_part[part*100 + mrow] = sum;
      }
      __syncthreads();
      if (tid < 25){
        float s0 = lds_part[tid]    + lds_part[100+tid] + lds_part[200+tid] + lds_part[300+tid];
        float s1 = lds_part[25+tid] + lds_part[125+tid] + lds_part[225+tid] + lds_part[325+tid];
        float s2 = lds_part[50+tid] + lds_part[150+tid] + lds_part[250+tid] + lds_part[350+tid];
        float s3 = lds_part[75+tid] + lds_part[175+tid] + lds_part[275+tid] + lds_part[375+tid];
        float gi = bi+s0, gf = bf+s1, gg = bg+s2, go = bo+s3;
        c = fsig(gf)*c + fsig(gi)*ftanh(gg);
        float h = fsig(go)*ftanh(c);
        RN[(size_t)t*HID + j] = h;
        pub_tag(hbufB + (size_t)((t+1)&7)*HID + j, (unsigned)(t+1), h);
        lds_hnew[tid] = h;
      }
      __syncthreads();
    }
  }
}

// ---------------- rtoken = RN @ fcW.T + fcb  (f32) ----------------
__global__ void __launch_bounds__(256) krtoken(
    const float* __restrict__ RN, const float* __restrict__ fcW,
    const float* __restrict__ fcb, float* __restrict__ out)
{
  __shared__ float xs[8*400];
  const int t0 = blockIdx.x*8;
  const int tid = threadIdx.x;
  for (int idx = tid; idx < 8*400; idx += 256)
    xs[idx] = RN[(size_t)t0*400 + idx];
  __syncthreads();
  if (tid >= 150) return;
  float acc[8];
  #pragma unroll
  for (int i=0;i<8;i++) acc[i]=0.f;
  const float4* wr = (const float4*)(fcW + (size_t)tid*400);
  for (int k4=0;k4<100;k4++){
    float4 w = wr[k4];
    #pragma unroll
    for (int tt=0;tt<8;tt++){
      const float4 x4 = *(const float4*)(xs + tt*400 + 4*k4);
      acc[tt] += w.x*x4.x + w.y*x4.y + w.z*x4.z + w.w*x4.w;
    }
  }
  float bb = fcb[tid];
  #pragma unroll
  for (int tt=0;tt<8;tt++)
    out[(size_t)(t0+tt)*150 + tid] = acc[tt] + bb;
}

// ---------------- per-t context scalar ----------------
__global__ void kfinal(const float* __restrict__ RN, const float* __restrict__ actW,
                       const float* __restrict__ actb, const float* __restrict__ Dp,
                       float* __restrict__ vbuf)
{
  int t = blockIdx.x, l = threadIdx.x;
  const float* r = RN + (size_t)t*HID;
  float s0=0.f, s1=0.f, s2=0.f, sd=0.f;
  for (int k=l; k<HID; k+=64){
    float rv = r[k];
    s0 += actW[k]*rv;
    s1 += actW[400+k]*rv;
    s2 += actW[800+k]*rv;
    sd += Dp[k]*rv;
  }
  #pragma unroll
  for (int o=1;o<64;o<<=1){
    s0 += __shfl_xor(s0,o); s1 += __shfl_xor(s1,o);
    s2 += __shfl_xor(s2,o); sd += __shfl_xor(sd,o);
  }
  if (l==0){
    s0 += actb[0]; s1 += actb[1]; s2 += actb[2];
    float m = fmaxf(s0, fmaxf(s1, s2));
    float e0 = __expf(s0-m), e1 = __expf(s1-m), e2 = __expf(s2-m);
    float p0 = e0/(e0+e1+e2);
    vbuf[t] = p0 * fsig(sd);
  }
}

// ---------------- context write: zero + slot0 broadcast (f32). LAST kernel. ----------------
__global__ void kctx(const float* __restrict__ vbuf, uint4* __restrict__ ctx, int n16){
  int i = blockIdx.x*256 + threadIdx.x;
  int stride = gridDim.x*256;
  for (; i<n16; i+=stride){
    int t = i / 3200;
    int p = i - t*3200;
    uint4 z;
    if (p < 100){
      float v = vbuf[t];
      union{float f; uint32_t u;} cv; cv.f = v;
      z.x = z.y = z.z = z.w = cv.u;
    } else {
      z.x = z.y = z.z = z.w = 0u;
    }
    ctx[i] = z;
  }
}

// ---------------- key LSTM (1 step, h0=c0=0 so key_Whh is dead) + fc (f32) ----------------
__global__ void __launch_bounds__(512) kkey(
    const float* __restrict__ RN, const float* __restrict__ Wih,
    const float* __restrict__ bih, const float* __restrict__ bhh,
    const float* __restrict__ fcW, const float* __restrict__ fcb,
    float* __restrict__ out)
{
  __shared__ float rh[HID];
  __shared__ float gk[4*KDIM];
  __shared__ float hk[KDIM];
  int tid = threadIdx.x;
  if (tid < HID) rh[tid] = RN[(size_t)(T_LEN-1)*HID + tid];
  __syncthreads();
  for (int r = tid; r < 4*KDIM; r += 512){
    const float4* wr = (const float4*)(Wih + (size_t)r*HID);
    float acc = 0.f;
    for (int k4=0;k4<100;k4++){
      float4 w = wr[k4];
      const float4 x4 = *(const float4*)(rh + 4*k4);
      acc += w.x*x4.x + w.y*x4.y + w.z*x4.z + w.w*x4.w;
    }
    gk[r] = acc + bih[r] + bhh[r];
  }
  __syncthreads();
  if (tid < KDIM){
    float gi = gk[tid], gg = gk[2*KDIM+tid], go = gk[3*KDIM+tid];
    float cc = fsig(gi)*ftanh(gg);
    hk[tid] = fsig(go)*ftanh(cc);
  }
  __syncthreads();
  if (tid < HID){
    const float4* wr = (const float4*)(fcW + (size_t)tid*KDIM);
    float acc = 0.f;
    for (int k4=0;k4<75;k4++){
      float4 w = wr[k4];
      const float4 x4 = *(const float4*)(hk + 4*k4);
      acc += w.x*x4.x + w.y*x4.y + w.z*x4.z + w.w*x4.w;
    }
    out[tid] = acc + fcb[tid];
  }
}

extern "C" void kernel_launch(void* const* d_in, const int* in_sizes, int n_in,
                              void* d_out, int out_size, void* d_ws, size_t ws_size,
                              hipStream_t stream)
{
  (void)in_sizes; (void)n_in; (void)ws_size;
  const int*   xr   = (const int*)d_in[0];
  const int*   xcpc = (const int*)d_in[1];
  const int*   xma  = (const int*)d_in[2];
  const float* em   = (const float*)d_in[3];
  const float* ec   = (const float*)d_in[4];
  const float* er   = (const float*)d_in[5];
  const float* Wih0 = (const float*)d_in[6];
  const float* Whh0 = (const float*)d_in[7];
  const float* bih0 = (const float*)d_in[8];
  const float* bhh0 = (const float*)d_in[9];
  const float* Wih1 = (const float*)d_in[10];
  const float* Whh1 = (const float*)d_in[11];
  const float* bih1 = (const float*)d_in[12];
  const float* bhh1 = (const float*)d_in[13];
  const float* fcW  = (const float*)d_in[14];
  const float* fcb  = (const float*)d_in[15];
  const float* actW = (const float*)d_in[16];
  const float* actb = (const float*)d_in[17];
  const float* Dp   = (const float*)d_in[18];
  const float* kWih = (const float*)d_in[19];
  /* d_in[20] key_Whh unused: h0 = 0 for the single key step */
  const float* kbih = (const float*)d_in[21];
  const float* kbhh = (const float*)d_in[22];
  const float* kfcW = (const float*)d_in[23];
  const float* kfcb = (const float*)d_in[24];

  float* vbuf = (float*)d_ws;                           // 16 KB in ws

  // ---- large scratch + handshake bufs in TAIL of d_out's ctx region; kctx rewrites last ----
  float* out = (float*)d_out;
  char*  ob  = (char*)d_out;
  size_t total = (size_t)out_size * 4;                  // 212,174,400 bytes
  float* XG0 = (float*)(ob + total - 26214400);         // 4096*1600 f32
  float* RN  = (float*)(ob + total - 32768000);         // 4096*400 f32
  char*  ctl = ob + total - 32768000 - 262144;          // control block (256 KB reserve)
  unsigned long long* hbufA = (unsigned long long*)(ctl);            // 8*400*8 = 25,600 B
  unsigned long long* hbufB = (unsigned long long*)(ctl + 25600);    // 25,600 B
  unsigned* l1p = (unsigned*)(ctl + 51200);                          // 64 u32

  float* rtok = out;                 // 4096*150
  float* ktok = out + 614400;        // 400
  uint4* ctxp = (uint4*)(ob + 614800u*4u);              // ctx region, 209,715,200 B
  int n16 = (int)((total - 614800u*4u) >> 4);           // 13,107,200

  dim3 gg(T_LEN/8, 7);
  kgemm0<<<gg,256,0,stream>>>(xma, xcpc, xr, em, ec, er, Wih0, bih0, bhh0, XG0);
  kinit<<<1,64,0,stream>>>(l1p);
  kpipe<<<32,512,0,stream>>>(XG0, Whh0, Whh1, Wih1, bih1, bhh1, RN,
                             hbufA, hbufB, l1p, T_LEN);
  krtoken<<<T_LEN/8,256,0,stream>>>(RN, fcW, fcb, rtok);
  kkey<<<1,512,0,stream>>>(RN, kWih, kbih, kbhh, kfcW, kfcb, ktok);
  kfinal<<<T_LEN,64,0,stream>>>(RN, actW, actb, Dp, vbuf);
  kctx<<<2048,256,0,stream>>>(vbuf, ctxp, n16);
}

// Round 8
// 9784.496 us; speedup vs baseline: 1.2032x; 1.2032x over previous
//
#include <hip/hip_runtime.h>
#include <stdint.h>

#define T_LEN 4096
#define HID   400
#define G4    1600
#define KDIM  300
#define STACKN 32

__device__ __forceinline__ float fsig(float x){ return 1.f/(1.f + __expf(-x)); }
__device__ __forceinline__ float ftanh(float x){ float e = __expf(2.f*x); return 1.f - 2.f/(e+1.f); }

// Software-pipelined tag poll: keep ~3 loads in flight; check oldest first.
// Same-address loads complete in order, so e0 is always the oldest sample.
// Cuts detect quantization from ~1 full load RTT to ~RTT/3.
__device__ __forceinline__ float wait_tag(const unsigned long long* p, unsigned want){
  unsigned long long e0 = __hip_atomic_load(p, __ATOMIC_RELAXED, __HIP_MEMORY_SCOPE_AGENT);
  unsigned long long e1 = __hip_atomic_load(p, __ATOMIC_RELAXED, __HIP_MEMORY_SCOPE_AGENT);
  unsigned long long e2 = __hip_atomic_load(p, __ATOMIC_RELAXED, __HIP_MEMORY_SCOPE_AGENT);
  unsigned long long e3 = __hip_atomic_load(p, __ATOMIC_RELAXED, __HIP_MEMORY_SCOPE_AGENT);
  while ((unsigned)(e0 >> 32) != want){
    e0 = e1; e1 = e2; e2 = e3;
    e3 = __hip_atomic_load(p, __ATOMIC_RELAXED, __HIP_MEMORY_SCOPE_AGENT);
  }
  union{unsigned u; float f;} c; c.u = (unsigned)e0; return c.f;
}
__device__ __forceinline__ void pub_tag(unsigned long long* p, unsigned tag, float v){
  union{unsigned u; float f;} c; c.f = v;
  __hip_atomic_store(p, ((unsigned long long)tag << 32) | (unsigned long long)c.u,
                     __ATOMIC_RELAXED, __HIP_MEMORY_SCOPE_AGENT);
}

// ---------------- layer-0 xg GEMM with fused embedding gather (K=150, f32) ----------------
__global__ void __launch_bounds__(256) kgemm0(
    const int* __restrict__ xma, const int* __restrict__ xcpc, const int* __restrict__ xr,
    const float* __restrict__ em, const float* __restrict__ ec, const float* __restrict__ er,
    const float* __restrict__ W, const float* __restrict__ b1, const float* __restrict__ b2,
    float* __restrict__ XG)
{
  __shared__ float xs[8*152];
  const int t0 = blockIdx.x*8;
  const int tid = threadIdx.x;
  for (int idx = tid; idx < 8*150; idx += 256){
    int tt = idx / 150, k = idx - tt*150;
    int t = t0 + tt;
    float v;
    if (k < 50)       v = em[(size_t)xma[t]*50 + k];
    else if (k < 100) v = ec[(size_t)xcpc[t]*50 + (k-50)];
    else              v = er[(size_t)xr[t]*50 + (k-100)];
    xs[tt*152 + k] = v;
  }
  __syncthreads();
  int r = blockIdx.y*256 + tid;
  if (r >= G4) return;
  float acc[8];
  #pragma unroll
  for (int i=0;i<8;i++) acc[i]=0.f;
  const float2* wr = (const float2*)(W + (size_t)r*150);
  for (int k2=0;k2<75;k2++){
    float2 w = wr[k2];
    int k = 2*k2;
    #pragma unroll
    for (int tt=0;tt<8;tt++)
      acc[tt] += w.x*xs[tt*152+k] + w.y*xs[tt*152+k+1];
  }
  float bb = b1[r] + b2[r];
  #pragma unroll
  for (int tt=0;tt<8;tt++)
    XG[(size_t)(t0+tt)*G4 + r] = acc[tt] + bb;
}

// ================== fused 2-layer pipelined LSTM scan (round-4 dataflow, verbatim) ==========
// 48 WGs: [0,16) L0 recurrence; [16,32) FF (xg1 = Wih1 @ h0_t + biases); [32,48) L1 recurrence.
// Tagged handshake: u64 {tag hi32, f32 lo32}, relaxed agent atomics, depth-8 slot buffers.
// Tags 1..T never collide with 0x00/0xAA fill. The ONLY change vs round 4 is the pipelined
// wait_tag (see above) — no credits, no matvec remap, no stage folding (rounds 6/7 showed each
// of those adds a serialized RTT to the limiting stage's chain).
__global__ void __launch_bounds__(512,1) kpipe(
    const float* __restrict__ XG0,
    const float* __restrict__ Whh0, const float* __restrict__ Whh1,
    const float* __restrict__ Wih1, const float* __restrict__ bih1,
    const float* __restrict__ bhh1,
    float* __restrict__ RN,
    unsigned long long* hbufA, unsigned long long* hbufB,
    unsigned long long* gbuf, int T)
{
  const int wid = blockIdx.x;
  const int tid = threadIdx.x;
  const int row_local = tid >> 2;    // 0..127 (100 used)
  const int part = tid & 3;          // k-slice of 100
  const bool mat = (row_local < 100);

  __shared__ float lds_h[400];
  __shared__ float lds_g[100];
  __shared__ float lds_xg[100];
  __shared__ float lds_hnew[25];

  if (wid < 16){
    // ---------- layer-0 recurrence ----------
    const int w = wid;
    float wreg[100];
    if (mat){
      int gate = row_local/25, jj = row_local%25;
      int row = gate*400 + w*25 + jj;
      const float4* wr = (const float4*)(Whh0 + (size_t)row*HID) + part*25;
      #pragma unroll
      for (int i=0;i<25;i++){
        float4 v = wr[i];
        wreg[4*i]=v.x; wreg[4*i+1]=v.y; wreg[4*i+2]=v.z; wreg[4*i+3]=v.w;
      }
    }
    const bool ew = (tid < 25);
    const int j = w*25 + tid;
    float c = 0.f;
    for (int t=0; t<T; t++){
      float xgi=0.f, xgf=0.f, xgg=0.f, xgo=0.f;
      if (ew){
        const float* xrw = XG0 + (size_t)t*G4;
        xgi = xrw[j]; xgf = xrw[HID+j]; xgg = xrw[2*HID+j]; xgo = xrw[3*HID+j];
      }
      if (tid < HID){
        float hv = 0.f;
        if (t > 0){
          if (tid >= w*25 && tid < w*25+25) hv = lds_hnew[tid - w*25];
          else hv = wait_tag(hbufA + (size_t)(t&7)*HID + tid, (unsigned)t);
        }
        lds_h[tid] = hv;
      }
      __syncthreads();
      float sum = 0.f;
      if (mat){
        const float4* hp = (const float4*)(lds_h + part*100);
        #pragma unroll
        for (int i=0;i<25;i++){
          float4 h4 = hp[i];
          sum += wreg[4*i]*h4.x + wreg[4*i+1]*h4.y + wreg[4*i+2]*h4.z + wreg[4*i+3]*h4.w;
        }
      }
      sum += __shfl_xor(sum, 1);
      sum += __shfl_xor(sum, 2);
      if (mat && part==0) lds_g[row_local] = sum;
      __syncthreads();
      if (ew){
        float gi = xgi + lds_g[tid];
        float gf = xgf + lds_g[25+tid];
        float gg = xgg + lds_g[50+tid];
        float go = xgo + lds_g[75+tid];
        float si = fsig(gi), sf = fsig(gf), so = fsig(go), tg = ftanh(gg);
        c = sf*c + si*tg;
        float h = so*ftanh(c);
        lds_hnew[tid] = h;
        pub_tag(hbufA + (size_t)((t+1)&7)*HID + j, (unsigned)(t+1), h);
      }
      __syncthreads();
    }
  } else if (wid < 32){
    // ---------- FF: xg1_t = Wih1(own 100 rows) @ h0_t + bih1 + bhh1 ----------
    const int f = wid - 16;
    float wreg[100];
    float bias = 0.f;
    int grow = 0;
    if (mat){
      int gate = row_local/25, jj = row_local%25;
      grow = gate*400 + f*25 + jj;
      const float4* wr = (const float4*)(Wih1 + (size_t)grow*HID) + part*25;
      #pragma unroll
      for (int i=0;i<25;i++){
        float4 v = wr[i];
        wreg[4*i]=v.x; wreg[4*i+1]=v.y; wreg[4*i+2]=v.z; wreg[4*i+3]=v.w;
      }
      if (part==0) bias = bih1[grow] + bhh1[grow];
    }
    for (int t=0; t<T; t++){
      if (tid < HID)
        lds_h[tid] = wait_tag(hbufA + (size_t)((t+1)&7)*HID + tid, (unsigned)(t+1));
      __syncthreads();
      float sum = 0.f;
      if (mat){
        const float4* hp = (const float4*)(lds_h + part*100);
        #pragma unroll
        for (int i=0;i<25;i++){
          float4 h4 = hp[i];
          sum += wreg[4*i]*h4.x + wreg[4*i+1]*h4.y + wreg[4*i+2]*h4.z + wreg[4*i+3]*h4.w;
        }
      }
      sum += __shfl_xor(sum, 1);
      sum += __shfl_xor(sum, 2);
      if (mat && part==0){
        pub_tag(gbuf + (size_t)((t+1)&7)*G4 + grow, (unsigned)(t+1), sum + bias);
      }
      __syncthreads();
    }
  } else {
    // ---------- layer-1 recurrence ----------
    const int l = wid - 32;
    float wreg[100];
    if (mat){
      int gate = row_local/25, jj = row_local%25;
      int row = gate*400 + l*25 + jj;
      const float4* wr = (const float4*)(Whh1 + (size_t)row*HID) + part*25;
      #pragma unroll
      for (int i=0;i<25;i++){
        float4 v = wr[i];
        wreg[4*i]=v.x; wreg[4*i+1]=v.y; wreg[4*i+2]=v.z; wreg[4*i+3]=v.w;
      }
    }
    const bool ew = (tid < 25);
    const int j = l*25 + tid;
    float c = 0.f;
    for (int t=0; t<T; t++){
      if (tid < HID){
        float hv = 0.f;
        if (t > 0){
          if (tid >= l*25 && tid < l*25+25) hv = lds_hnew[tid - l*25];
          else hv = wait_tag(hbufB + (size_t)(t&7)*HID + tid, (unsigned)t);
        }
        lds_h[tid] = hv;
      } else if (tid < 500){
        int i = tid - 400;               // local row: gate*25 + jj
        int gate = i/25, jj = i - gate*25;
        lds_xg[i] = wait_tag(gbuf + (size_t)((t+1)&7)*G4 + gate*400 + l*25 + jj,
                             (unsigned)(t+1));
      }
      __syncthreads();
      float sum = 0.f;
      if (mat){
        const float4* hp = (const float4*)(lds_h + part*100);
        #pragma unroll
        for (int i=0;i<25;i++){
          float4 h4 = hp[i];
          sum += wreg[4*i]*h4.x + wreg[4*i+1]*h4.y + wreg[4*i+2]*h4.z + wreg[4*i+3]*h4.w;
        }
      }
      sum += __shfl_xor(sum, 1);
      sum += __shfl_xor(sum, 2);
      if (mat && part==0) lds_g[row_local] = sum;
      __syncthreads();
      if (ew){
        float gi = lds_xg[tid]    + lds_g[tid];
        float gf = lds_xg[25+tid] + lds_g[25+tid];
        float gg = lds_xg[50+tid] + lds_g[50+tid];
        float go = lds_xg[75+tid] + lds_g[75+tid];
        float si = fsig(gi), sf = fsig(gf), so = fsig(go), tg = ftanh(gg);
        c = sf*c + si*tg;
        float h = so*ftanh(c);
        lds_hnew[tid] = h;
        RN[(size_t)t*HID + j] = h;
        pub_tag(hbufB + (size_t)((t+1)&7)*HID + j, (unsigned)(t+1), h);
      }
      __syncthreads();
    }
  }
}

// ---------------- rtoken = RN @ fcW.T + fcb  (f32) ----------------
__global__ void __launch_bounds__(256) krtoken(
    const float* __restrict__ RN, const float* __restrict__ fcW,
    const float* __restrict__ fcb, float* __restrict__ out)
{
  __shared__ float xs[8*400];
  const int t0 = blockIdx.x*8;
  const int tid = threadIdx.x;
  for (int idx = tid; idx < 8*400; idx += 256)
    xs[idx] = RN[(size_t)t0*400 + idx];
  __syncthreads();
  if (tid >= 150) return;
  float acc[8];
  #pragma unroll
  for (int i=0;i<8;i++) acc[i]=0.f;
  const float4* wr = (const float4*)(fcW + (size_t)tid*400);
  for (int k4=0;k4<100;k4++){
    float4 w = wr[k4];
    #pragma unroll
    for (int tt=0;tt<8;tt++){
      const float4 x4 = *(const float4*)(xs + tt*400 + 4*k4);
      acc[tt] += w.x*x4.x + w.y*x4.y + w.z*x4.z + w.w*x4.w;
    }
  }
  float bb = fcb[tid];
  #pragma unroll
  for (int tt=0;tt<8;tt++)
    out[(size_t)(t0+tt)*150 + tid] = acc[tt] + bb;
}

// ---------------- per-t context scalar ----------------
__global__ void kfinal(const float* __restrict__ RN, const float* __restrict__ actW,
                       const float* __restrict__ actb, const float* __restrict__ Dp,
                       float* __restrict__ vbuf)
{
  int t = blockIdx.x, l = threadIdx.x;
  const float* r = RN + (size_t)t*HID;
  float s0=0.f, s1=0.f, s2=0.f, sd=0.f;
  for (int k=l; k<HID; k+=64){
    float rv = r[k];
    s0 += actW[k]*rv;
    s1 += actW[400+k]*rv;
    s2 += actW[800+k]*rv;
    sd += Dp[k]*rv;
  }
  #pragma unroll
  for (int o=1;o<64;o<<=1){
    s0 += __shfl_xor(s0,o); s1 += __shfl_xor(s1,o);
    s2 += __shfl_xor(s2,o); sd += __shfl_xor(sd,o);
  }
  if (l==0){
    s0 += actb[0]; s1 += actb[1]; s2 += actb[2];
    float m = fmaxf(s0, fmaxf(s1, s2));
    float e0 = __expf(s0-m), e1 = __expf(s1-m), e2 = __expf(s2-m);
    float p0 = e0/(e0+e1+e2);
    vbuf[t] = p0 * fsig(sd);
  }
}

// ---------------- context write: zero + slot0 broadcast (f32). LAST kernel. ----------------
__global__ void kctx(const float* __restrict__ vbuf, uint4* __restrict__ ctx, int n16){
  int i = blockIdx.x*256 + threadIdx.x;
  int stride = gridDim.x*256;
  for (; i<n16; i+=stride){
    int t = i / 3200;
    int p = i - t*3200;
    uint4 z;
    if (p < 100){
      float v = vbuf[t];
      union{float f; uint32_t u;} cv; cv.f = v;
      z.x = z.y = z.z = z.w = cv.u;
    } else {
      z.x = z.y = z.z = z.w = 0u;
    }
    ctx[i] = z;
  }
}

// ---------------- key LSTM (1 step, h0=c0=0 so key_Whh is dead) + fc (f32) ----------------
__global__ void __launch_bounds__(512) kkey(
    const float* __restrict__ RN, const float* __restrict__ Wih,
    const float* __restrict__ bih, const float* __restrict__ bhh,
    const float* __restrict__ fcW, const float* __restrict__ fcb,
    float* __restrict__ out)
{
  __shared__ float rh[HID];
  __shared__ float gk[4*KDIM];
  __shared__ float hk[KDIM];
  int tid = threadIdx.x;
  if (tid < HID) rh[tid] = RN[(size_t)(T_LEN-1)*HID + tid];
  __syncthreads();
  for (int r = tid; r < 4*KDIM; r += 512){
    const float4* wr = (const float4*)(Wih + (size_t)r*HID);
    float acc = 0.f;
    for (int k4=0;k4<100;k4++){
      float4 w = wr[k4];
      const float4 x4 = *(const float4*)(rh + 4*k4);
      acc += w.x*x4.x + w.y*x4.y + w.z*x4.z + w.w*x4.w;
    }
    gk[r] = acc + bih[r] + bhh[r];
  }
  __syncthreads();
  if (tid < KDIM){
    float gi = gk[tid], gg = gk[2*KDIM+tid], go = gk[3*KDIM+tid];
    float cc = fsig(gi)*ftanh(gg);
    hk[tid] = fsig(go)*ftanh(cc);
  }
  __syncthreads();
  if (tid < HID){
    const float4* wr = (const float4*)(fcW + (size_t)tid*KDIM);
    float acc = 0.f;
    for (int k4=0;k4<75;k4++){
      float4 w = wr[k4];
      const float4 x4 = *(const float4*)(hk + 4*k4);
      acc += w.x*x4.x + w.y*x4.y + w.z*x4.z + w.w*x4.w;
    }
    out[tid] = acc + fcb[tid];
  }
}

extern "C" void kernel_launch(void* const* d_in, const int* in_sizes, int n_in,
                              void* d_out, int out_size, void* d_ws, size_t ws_size,
                              hipStream_t stream)
{
  (void)in_sizes; (void)n_in; (void)ws_size;
  const int*   xr   = (const int*)d_in[0];
  const int*   xcpc = (const int*)d_in[1];
  const int*   xma  = (const int*)d_in[2];
  const float* em   = (const float*)d_in[3];
  const float* ec   = (const float*)d_in[4];
  const float* er   = (const float*)d_in[5];
  const float* Wih0 = (const float*)d_in[6];
  const float* Whh0 = (const float*)d_in[7];
  const float* bih0 = (const float*)d_in[8];
  const float* bhh0 = (const float*)d_in[9];
  const float* Wih1 = (const float*)d_in[10];
  const float* Whh1 = (const float*)d_in[11];
  const float* bih1 = (const float*)d_in[12];
  const float* bhh1 = (const float*)d_in[13];
  const float* fcW  = (const float*)d_in[14];
  const float* fcb  = (const float*)d_in[15];
  const float* actW = (const float*)d_in[16];
  const float* actb = (const float*)d_in[17];
  const float* Dp   = (const float*)d_in[18];
  const float* kWih = (const float*)d_in[19];
  /* d_in[20] key_Whh unused: h0 = 0 for the single key step */
  const float* kbih = (const float*)d_in[21];
  const float* kbhh = (const float*)d_in[22];
  const float* kfcW = (const float*)d_in[23];
  const float* kfcb = (const float*)d_in[24];

  float* vbuf = (float*)d_ws;                           // 16 KB in ws

  // ---- large scratch + handshake bufs in TAIL of d_out's ctx region; kctx rewrites last ----
  float* out = (float*)d_out;
  char*  ob  = (char*)d_out;
  size_t total = (size_t)out_size * 4;                  // 212,174,400 bytes
  float* XG0 = (float*)(ob + total - 26214400);         // 4096*1600 f32
  float* RN  = (float*)(ob + total - 32768000);         // 4096*400 f32
  char*  ctl = ob + total - 32768000 - 262144;          // control block (256 KB reserve)
  unsigned long long* hbufA = (unsigned long long*)(ctl);            // 8*400*8 = 25,600 B
  unsigned long long* hbufB = (unsigned long long*)(ctl + 25600);    // 25,600 B
  unsigned long long* gbuf  = (unsigned long long*)(ctl + 51200);    // 8*1600*8 = 102,400 B

  float* rtok = out;                 // 4096*150
  float* ktok = out + 614400;        // 400
  uint4* ctxp = (uint4*)(ob + 614800u*4u);              // ctx region, 209,715,200 B
  int n16 = (int)((total - 614800u*4u) >> 4);           // 13,107,200

  dim3 gg(T_LEN/8, 7);
  kgemm0<<<gg,256,0,stream>>>(xma, xcpc, xr, em, ec, er, Wih0, bih0, bhh0, XG0);
  kpipe<<<48,512,0,stream>>>(XG0, Whh0, Whh1, Wih1, bih1, bhh1, RN,
                             hbufA, hbufB, gbuf, T_LEN);
  krtoken<<<T_LEN/8,256,0,stream>>>(RN, fcW, fcb, rtok);
  kkey<<<1,512,0,stream>>>(RN, kWih, kbih, kbhh, kfcW, kfcb, ktok);
  kfinal<<<T_LEN,64,0,stream>>>(RN, actW, actb, Dp, vbuf);
  kctx<<<2048,256,0,stream>>>(vbuf, ctxp, n16);
}

// Round 9
// 8334.074 us; speedup vs baseline: 1.4126x; 1.1740x over previous
//
#include <hip/hip_runtime.h>
#include <stdint.h>

#define T_LEN 4096
#define HID   400
#define G4    1600
#define KDIM  300
#define STACKN 32

__device__ __forceinline__ float fsig(float x){ return 1.f/(1.f + __expf(-x)); }
__device__ __forceinline__ float ftanh(float x){ float e = __expf(2.f*x); return 1.f - 2.f/(e+1.f); }

// Single-load tag spin (R4-proven). R8 showed multi-load pipelining INCREASES period:
// agent-atomic poll traffic contends at the coherence point; keep exactly one in flight.
__device__ __forceinline__ float wait_tag(const unsigned long long* p, unsigned want){
  unsigned long long ex;
  do { ex = __hip_atomic_load(p, __ATOMIC_RELAXED, __HIP_MEMORY_SCOPE_AGENT); }
  while ((unsigned)(ex >> 32) != want);
  union{unsigned u; float f;} c; c.u = (unsigned)ex; return c.f;
}
__device__ __forceinline__ void pub_tag(unsigned long long* p, unsigned tag, float v){
  union{unsigned u; float f;} c; c.f = v;
  __hip_atomic_store(p, ((unsigned long long)tag << 32) | (unsigned long long)c.u,
                     __ATOMIC_RELAXED, __HIP_MEMORY_SCOPE_AGENT);
}

// LDS-only workgroup barrier: s_waitcnt lgkmcnt(0) + s_barrier, NO vmcnt(0) drain.
// __syncthreads() drains vmcnt(0), which serializes the publisher's agent-scope
// pub store completion (~700 cyc to IF$) into its own per-step loop. All cross-wave
// dependencies inside the scan step are through LDS; global-load results are waited
// on at their use sites by compiler-inserted vmcnt. So LDS-only ordering suffices.
__device__ __forceinline__ void bar(){
  asm volatile("s_waitcnt lgkmcnt(0)\n\ts_barrier" ::: "memory");
}

// ---------------- layer-0 xg GEMM with fused embedding gather (K=150, f32) ----------------
__global__ void __launch_bounds__(256) kgemm0(
    const int* __restrict__ xma, const int* __restrict__ xcpc, const int* __restrict__ xr,
    const float* __restrict__ em, const float* __restrict__ ec, const float* __restrict__ er,
    const float* __restrict__ W, const float* __restrict__ b1, const float* __restrict__ b2,
    float* __restrict__ XG)
{
  __shared__ float xs[8*152];
  const int t0 = blockIdx.x*8;
  const int tid = threadIdx.x;
  for (int idx = tid; idx < 8*150; idx += 256){
    int tt = idx / 150, k = idx - tt*150;
    int t = t0 + tt;
    float v;
    if (k < 50)       v = em[(size_t)xma[t]*50 + k];
    else if (k < 100) v = ec[(size_t)xcpc[t]*50 + (k-50)];
    else              v = er[(size_t)xr[t]*50 + (k-100)];
    xs[tt*152 + k] = v;
  }
  __syncthreads();
  int r = blockIdx.y*256 + tid;
  if (r >= G4) return;
  float acc[8];
  #pragma unroll
  for (int i=0;i<8;i++) acc[i]=0.f;
  const float2* wr = (const float2*)(W + (size_t)r*150);
  for (int k2=0;k2<75;k2++){
    float2 w = wr[k2];
    int k = 2*k2;
    #pragma unroll
    for (int tt=0;tt<8;tt++)
      acc[tt] += w.x*xs[tt*152+k] + w.y*xs[tt*152+k+1];
  }
  float bb = b1[r] + b2[r];
  #pragma unroll
  for (int tt=0;tt<8;tt++)
    XG[(size_t)(t0+tt)*G4 + r] = acc[tt] + bb;
}

// ================== fused 2-layer pipelined LSTM scan (round-4 dataflow) ==================
// 48 WGs: [0,16) L0 recurrence; [16,32) FF (xg1 = Wih1 @ h0_t + biases); [32,48) L1 recurrence.
// Tagged handshake: u64 {tag hi32, f32 lo32}, relaxed agent atomics, depth-8 slot buffers.
// Tags 1..T never collide with 0x00/0xAA fill. ONLY change vs round 4: in-loop barriers are
// LDS-only (bar(), no vmcnt drain) and wait_tag is the proven single-load spin.
__global__ void __launch_bounds__(512,1) kpipe(
    const float* __restrict__ XG0,
    const float* __restrict__ Whh0, const float* __restrict__ Whh1,
    const float* __restrict__ Wih1, const float* __restrict__ bih1,
    const float* __restrict__ bhh1,
    float* __restrict__ RN,
    unsigned long long* hbufA, unsigned long long* hbufB,
    unsigned long long* gbuf, int T)
{
  const int wid = blockIdx.x;
  const int tid = threadIdx.x;
  const int row_local = tid >> 2;    // 0..127 (100 used)
  const int part = tid & 3;          // k-slice of 100
  const bool mat = (row_local < 100);

  __shared__ float lds_h[400];
  __shared__ float lds_g[100];
  __shared__ float lds_xg[100];
  __shared__ float lds_hnew[25];

  if (wid < 16){
    // ---------- layer-0 recurrence ----------
    const int w = wid;
    float wreg[100];
    if (mat){
      int gate = row_local/25, jj = row_local%25;
      int row = gate*400 + w*25 + jj;
      const float4* wr = (const float4*)(Whh0 + (size_t)row*HID) + part*25;
      #pragma unroll
      for (int i=0;i<25;i++){
        float4 v = wr[i];
        wreg[4*i]=v.x; wreg[4*i+1]=v.y; wreg[4*i+2]=v.z; wreg[4*i+3]=v.w;
      }
    }
    const bool ew = (tid < 25);
    const int j = w*25 + tid;
    float c = 0.f;
    for (int t=0; t<T; t++){
      float xgi=0.f, xgf=0.f, xgg=0.f, xgo=0.f;
      if (ew){
        const float* xrw = XG0 + (size_t)t*G4;
        xgi = xrw[j]; xgf = xrw[HID+j]; xgg = xrw[2*HID+j]; xgo = xrw[3*HID+j];
      }
      if (tid < HID){
        float hv = 0.f;
        if (t > 0){
          if (tid >= w*25 && tid < w*25+25) hv = lds_hnew[tid - w*25];
          else hv = wait_tag(hbufA + (size_t)(t&7)*HID + tid, (unsigned)t);
        }
        lds_h[tid] = hv;
      }
      bar();
      float sum = 0.f;
      if (mat){
        const float4* hp = (const float4*)(lds_h + part*100);
        #pragma unroll
        for (int i=0;i<25;i++){
          float4 h4 = hp[i];
          sum += wreg[4*i]*h4.x + wreg[4*i+1]*h4.y + wreg[4*i+2]*h4.z + wreg[4*i+3]*h4.w;
        }
      }
      sum += __shfl_xor(sum, 1);
      sum += __shfl_xor(sum, 2);
      if (mat && part==0) lds_g[row_local] = sum;
      bar();
      if (ew){
        float gi = xgi + lds_g[tid];
        float gf = xgf + lds_g[25+tid];
        float gg = xgg + lds_g[50+tid];
        float go = xgo + lds_g[75+tid];
        float si = fsig(gi), sf = fsig(gf), so = fsig(go), tg = ftanh(gg);
        c = sf*c + si*tg;
        float h = so*ftanh(c);
        lds_hnew[tid] = h;
        pub_tag(hbufA + (size_t)((t+1)&7)*HID + j, (unsigned)(t+1), h);
      }
      bar();
    }
  } else if (wid < 32){
    // ---------- FF: xg1_t = Wih1(own 100 rows) @ h0_t + bih1 + bhh1 ----------
    const int f = wid - 16;
    float wreg[100];
    float bias = 0.f;
    int grow = 0;
    if (mat){
      int gate = row_local/25, jj = row_local%25;
      grow = gate*400 + f*25 + jj;
      const float4* wr = (const float4*)(Wih1 + (size_t)grow*HID) + part*25;
      #pragma unroll
      for (int i=0;i<25;i++){
        float4 v = wr[i];
        wreg[4*i]=v.x; wreg[4*i+1]=v.y; wreg[4*i+2]=v.z; wreg[4*i+3]=v.w;
      }
      if (part==0) bias = bih1[grow] + bhh1[grow];
    }
    for (int t=0; t<T; t++){
      if (tid < HID)
        lds_h[tid] = wait_tag(hbufA + (size_t)((t+1)&7)*HID + tid, (unsigned)(t+1));
      bar();
      float sum = 0.f;
      if (mat){
        const float4* hp = (const float4*)(lds_h + part*100);
        #pragma unroll
        for (int i=0;i<25;i++){
          float4 h4 = hp[i];
          sum += wreg[4*i]*h4.x + wreg[4*i+1]*h4.y + wreg[4*i+2]*h4.z + wreg[4*i+3]*h4.w;
        }
      }
      sum += __shfl_xor(sum, 1);
      sum += __shfl_xor(sum, 2);
      if (mat && part==0){
        pub_tag(gbuf + (size_t)((t+1)&7)*G4 + grow, (unsigned)(t+1), sum + bias);
      }
      bar();
    }
  } else {
    // ---------- layer-1 recurrence ----------
    const int l = wid - 32;
    float wreg[100];
    if (mat){
      int gate = row_local/25, jj = row_local%25;
      int row = gate*400 + l*25 + jj;
      const float4* wr = (const float4*)(Whh1 + (size_t)row*HID) + part*25;
      #pragma unroll
      for (int i=0;i<25;i++){
        float4 v = wr[i];
        wreg[4*i]=v.x; wreg[4*i+1]=v.y; wreg[4*i+2]=v.z; wreg[4*i+3]=v.w;
      }
    }
    const bool ew = (tid < 25);
    const int j = l*25 + tid;
    float c = 0.f;
    for (int t=0; t<T; t++){
      if (tid < HID){
        float hv = 0.f;
        if (t > 0){
          if (tid >= l*25 && tid < l*25+25) hv = lds_hnew[tid - l*25];
          else hv = wait_tag(hbufB + (size_t)(t&7)*HID + tid, (unsigned)t);
        }
        lds_h[tid] = hv;
      } else if (tid < 500){
        int i = tid - 400;               // local row: gate*25 + jj
        int gate = i/25, jj = i - gate*25;
        lds_xg[i] = wait_tag(gbuf + (size_t)((t+1)&7)*G4 + gate*400 + l*25 + jj,
                             (unsigned)(t+1));
      }
      bar();
      float sum = 0.f;
      if (mat){
        const float4* hp = (const float4*)(lds_h + part*100);
        #pragma unroll
        for (int i=0;i<25;i++){
          float4 h4 = hp[i];
          sum += wreg[4*i]*h4.x + wreg[4*i+1]*h4.y + wreg[4*i+2]*h4.z + wreg[4*i+3]*h4.w;
        }
      }
      sum += __shfl_xor(sum, 1);
      sum += __shfl_xor(sum, 2);
      if (mat && part==0) lds_g[row_local] = sum;
      bar();
      if (ew){
        float gi = lds_xg[tid]    + lds_g[tid];
        float gf = lds_xg[25+tid] + lds_g[25+tid];
        float gg = lds_xg[50+tid] + lds_g[50+tid];
        float go = lds_xg[75+tid] + lds_g[75+tid];
        float si = fsig(gi), sf = fsig(gf), so = fsig(go), tg = ftanh(gg);
        c = sf*c + si*tg;
        float h = so*ftanh(c);
        lds_hnew[tid] = h;
        RN[(size_t)t*HID + j] = h;
        pub_tag(hbufB + (size_t)((t+1)&7)*HID + j, (unsigned)(t+1), h);
      }
      bar();
    }
  }
}

// ---------------- rtoken = RN @ fcW.T + fcb  (f32) ----------------
__global__ void __launch_bounds__(256) krtoken(
    const float* __restrict__ RN, const float* __restrict__ fcW,
    const float* __restrict__ fcb, float* __restrict__ out)
{
  __shared__ float xs[8*400];
  const int t0 = blockIdx.x*8;
  const int tid = threadIdx.x;
  for (int idx = tid; idx < 8*400; idx += 256)
    xs[idx] = RN[(size_t)t0*400 + idx];
  __syncthreads();
  if (tid >= 150) return;
  float acc[8];
  #pragma unroll
  for (int i=0;i<8;i++) acc[i]=0.f;
  const float4* wr = (const float4*)(fcW + (size_t)tid*400);
  for (int k4=0;k4<100;k4++){
    float4 w = wr[k4];
    #pragma unroll
    for (int tt=0;tt<8;tt++){
      const float4 x4 = *(const float4*)(xs + tt*400 + 4*k4);
      acc[tt] += w.x*x4.x + w.y*x4.y + w.z*x4.z + w.w*x4.w;
    }
  }
  float bb = fcb[tid];
  #pragma unroll
  for (int tt=0;tt<8;tt++)
    out[(size_t)(t0+tt)*150 + tid] = acc[tt] + bb;
}

// ---------------- per-t context scalar ----------------
__global__ void kfinal(const float* __restrict__ RN, const float* __restrict__ actW,
                       const float* __restrict__ actb, const float* __restrict__ Dp,
                       float* __restrict__ vbuf)
{
  int t = blockIdx.x, l = threadIdx.x;
  const float* r = RN + (size_t)t*HID;
  float s0=0.f, s1=0.f, s2=0.f, sd=0.f;
  for (int k=l; k<HID; k+=64){
    float rv = r[k];
    s0 += actW[k]*rv;
    s1 += actW[400+k]*rv;
    s2 += actW[800+k]*rv;
    sd += Dp[k]*rv;
  }
  #pragma unroll
  for (int o=1;o<64;o<<=1){
    s0 += __shfl_xor(s0,o); s1 += __shfl_xor(s1,o);
    s2 += __shfl_xor(s2,o); sd += __shfl_xor(sd,o);
  }
  if (l==0){
    s0 += actb[0]; s1 += actb[1]; s2 += actb[2];
    float m = fmaxf(s0, fmaxf(s1, s2));
    float e0 = __expf(s0-m), e1 = __expf(s1-m), e2 = __expf(s2-m);
    float p0 = e0/(e0+e1+e2);
    vbuf[t] = p0 * fsig(sd);
  }
}

// ---------------- context write: zero + slot0 broadcast (f32). LAST kernel. ----------------
__global__ void kctx(const float* __restrict__ vbuf, uint4* __restrict__ ctx, int n16){
  int i = blockIdx.x*256 + threadIdx.x;
  int stride = gridDim.x*256;
  for (; i<n16; i+=stride){
    int t = i / 3200;
    int p = i - t*3200;
    uint4 z;
    if (p < 100){
      float v = vbuf[t];
      union{float f; uint32_t u;} cv; cv.f = v;
      z.x = z.y = z.z = z.w = cv.u;
    } else {
      z.x = z.y = z.z = z.w = 0u;
    }
    ctx[i] = z;
  }
}

// ---------------- key LSTM (1 step, h0=c0=0 so key_Whh is dead) + fc (f32) ----------------
__global__ void __launch_bounds__(512) kkey(
    const float* __restrict__ RN, const float* __restrict__ Wih,
    const float* __restrict__ bih, const float* __restrict__ bhh,
    const float* __restrict__ fcW, const float* __restrict__ fcb,
    float* __restrict__ out)
{
  __shared__ float rh[HID];
  __shared__ float gk[4*KDIM];
  __shared__ float hk[KDIM];
  int tid = threadIdx.x;
  if (tid < HID) rh[tid] = RN[(size_t)(T_LEN-1)*HID + tid];
  __syncthreads();
  for (int r = tid; r < 4*KDIM; r += 512){
    const float4* wr = (const float4*)(Wih + (size_t)r*HID);
    float acc = 0.f;
    for (int k4=0;k4<100;k4++){
      float4 w = wr[k4];
      const float4 x4 = *(const float4*)(rh + 4*k4);
      acc += w.x*x4.x + w.y*x4.y + w.z*x4.z + w.w*x4.w;
    }
    gk[r] = acc + bih[r] + bhh[r];
  }
  __syncthreads();
  if (tid < KDIM){
    float gi = gk[tid], gg = gk[2*KDIM+tid], go = gk[3*KDIM+tid];
    float cc = fsig(gi)*ftanh(gg);
    hk[tid] = fsig(go)*ftanh(cc);
  }
  __syncthreads();
  if (tid < HID){
    const float4* wr = (const float4*)(fcW + (size_t)tid*KDIM);
    float acc = 0.f;
    for (int k4=0;k4<75;k4++){
      float4 w = wr[k4];
      const float4 x4 = *(const float4*)(hk + 4*k4);
      acc += w.x*x4.x + w.y*x4.y + w.z*x4.z + w.w*x4.w;
    }
    out[tid] = acc + fcb[tid];
  }
}

extern "C" void kernel_launch(void* const* d_in, const int* in_sizes, int n_in,
                              void* d_out, int out_size, void* d_ws, size_t ws_size,
                              hipStream_t stream)
{
  (void)in_sizes; (void)n_in; (void)ws_size;
  const int*   xr   = (const int*)d_in[0];
  const int*   xcpc = (const int*)d_in[1];
  const int*   xma  = (const int*)d_in[2];
  const float* em   = (const float*)d_in[3];
  const float* ec   = (const float*)d_in[4];
  const float* er   = (const float*)d_in[5];
  const float* Wih0 = (const float*)d_in[6];
  const float* Whh0 = (const float*)d_in[7];
  const float* bih0 = (const float*)d_in[8];
  const float* bhh0 = (const float*)d_in[9];
  const float* Wih1 = (const float*)d_in[10];
  const float* Whh1 = (const float*)d_in[11];
  const float* bih1 = (const float*)d_in[12];
  const float* bhh1 = (const float*)d_in[13];
  const float* fcW  = (const float*)d_in[14];
  const float* fcb  = (const float*)d_in[15];
  const float* actW = (const float*)d_in[16];
  const float* actb = (const float*)d_in[17];
  const float* Dp   = (const float*)d_in[18];
  const float* kWih = (const float*)d_in[19];
  /* d_in[20] key_Whh unused: h0 = 0 for the single key step */
  const float* kbih = (const float*)d_in[21];
  const float* kbhh = (const float*)d_in[22];
  const float* kfcW = (const float*)d_in[23];
  const float* kfcb = (const float*)d_in[24];

  float* vbuf = (float*)d_ws;                           // 16 KB in ws

  // ---- large scratch + handshake bufs in TAIL of d_out's ctx region; kctx rewrites last ----
  float* out = (float*)d_out;
  char*  ob  = (char*)d_out;
  size_t total = (size_t)out_size * 4;                  // 212,174,400 bytes
  float* XG0 = (float*)(ob + total - 26214400);         // 4096*1600 f32
  float* RN  = (float*)(ob + total - 32768000);         // 4096*400 f32
  char*  ctl = ob + total - 32768000 - 262144;          // control block (256 KB reserve)
  unsigned long long* hbufA = (unsigned long long*)(ctl);            // 8*400*8 = 25,600 B
  unsigned long long* hbufB = (unsigned long long*)(ctl + 25600);    // 25,600 B
  unsigned long long* gbuf  = (unsigned long long*)(ctl + 51200);    // 8*1600*8 = 102,400 B

  float* rtok = out;                 // 4096*150
  float* ktok = out + 614400;        // 400
  uint4* ctxp = (uint4*)(ob + 614800u*4u);              // ctx region, 209,715,200 B
  int n16 = (int)((total - 614800u*4u) >> 4);           // 13,107,200

  dim3 gg(T_LEN/8, 7);
  kgemm0<<<gg,256,0,stream>>>(xma, xcpc, xr, em, ec, er, Wih0, bih0, bhh0, XG0);
  kpipe<<<48,512,0,stream>>>(XG0, Whh0, Whh1, Wih1, bih1, bhh1, RN,
                             hbufA, hbufB, gbuf, T_LEN);
  krtoken<<<T_LEN/8,256,0,stream>>>(RN, fcW, fcb, rtok);
  kkey<<<1,512,0,stream>>>(RN, kWih, kbih, kbhh, kfcW, kfcb, ktok);
  kfinal<<<T_LEN,64,0,stream>>>(RN, actW, actb, Dp, vbuf);
  kctx<<<2048,256,0,stream>>>(vbuf, ctxp, n16);
}